// Round 9
// baseline (98.741 us; speedup 1.0000x reference)
//
#include <hip/hip_runtime.h>
#include <math.h>

#define BATCH 1024
#define DIM   256
#define NCL   50000
#define TOTC  100000   // 2*NC
#define NSLICE 16

typedef __attribute__((ext_vector_type(8)))  short bf16x8;   // 8 bf16 = 4 VGPR
typedef __attribute__((ext_vector_type(16))) float f32x16;   // 32x32 acc frag

__device__ __forceinline__ unsigned int f2bf(float f) {   // RNE f32 -> bf16
    unsigned int u = __float_as_uint(f);
    return (u + 0x7FFFu + ((u >> 16) & 1u)) >> 16;
}

// ---------------------------------------------------------------------------
// Kernel 1: normalize rows -> bf16 xn stored TRANSPOSED in k-panels:
// element (k, b) lives at panel p=k>>3, byte p*16384 + b*16 + (k&7)*2.
// A 32x32x16-MFMA B-fragment (col=lane&31, k=kk*16+hi*8..+7) is then ONE
// coalesced 16B load (512B runs across lanes). Also: target logits, zero
// sliced accumulators. One wave per batch row.
// ---------------------------------------------------------------------------
__global__ __launch_bounds__(64) void k_prep(const float* __restrict__ in,
                                             const int* __restrict__ tgt,
                                             const float* __restrict__ feats,
                                             unsigned short* __restrict__ xnT,
                                             float* __restrict__ Sx,
                                             float* __restrict__ z) {
    const int b = blockIdx.x;
    const int t = threadIdx.x;           // 0..63, 4 floats each (k = t*4..t*4+3)
    float4 v = *(const float4*)&in[b * DIM + t * 4];
    float ss = v.x * v.x + v.y * v.y + v.z * v.z + v.w * v.w;
#pragma unroll
    for (int o = 1; o < 64; o <<= 1) ss += __shfl_xor(ss, o, 64);
    const float sc = 1.0f / sqrtf(ss);
    float4 w;
    w.x = v.x * sc; w.y = v.y * sc; w.z = v.z * sc; w.w = v.w * sc;

    // panel write: panel = t>>1, within-row byte offset (t&1)*8
    uint2 p;
    p.x = f2bf(w.x) | (f2bf(w.y) << 16);
    p.y = f2bf(w.z) | (f2bf(w.w) << 16);
    *(uint2*)((char*)xnT + (t >> 1) * 16384 + b * 16 + (t & 1) * 8) = p;

    const int tb = tgt[b];
#pragma unroll
    for (int h = 0; h < 2; ++h) {
        const int row = tb + h * NCL;    // mean half rows [0,NC), hard [NC,2NC)
        float4 f = *(const float4*)&feats[row * DIM + t * 4];
        float d = w.x * f.x + w.y * f.y + w.z * f.z + w.w * f.w;
#pragma unroll
        for (int o = 1; o < 64; o <<= 1) d += __shfl_xor(d, o, 64);
        if (t == 0) z[b * 2 + h] = d * 20.0f;
    }
    // zero sliced accumulators: 16*1024*2 = 32768 floats over 1024 blocks
    if (t < 32) Sx[b * 32 + t] = 0.0f;
}

// ---------------------------------------------------------------------------
// Kernel 2: MFMA GEMM + fused sumexp.
// 782 blocks x 8 waves; block owns 128 clusters. A (feature rows, f32->bf16)
// staged ONCE into 64 KB LDS, PANEL-MAJOR (chunk-major) so fragment reads
// are contiguous 512B runs (conflict-free); ONE barrier; then barrier-free
// main loop. Each wave: ALL 128 cluster rows (Mf=4) x 64 batch cols (Nf=2),
// two passes over the 1024 batch. Per kk: 4 ds_read_b128 + 2 coalesced 16B
// global B loads (xnT, L2-resident) + 8 MFMA -> each A-read feeds 2 MFMAs,
// each block reads xn exactly once. acc = 128 AGPRs; ~free VGPRs pipeline
// the B loads. Sums -> statically-indexed sregs; atomics once at kernel end.
// ---------------------------------------------------------------------------
__global__ __launch_bounds__(512) void k_main(const unsigned short* __restrict__ xnT,
                                              const float* __restrict__ feats,
                                              float* __restrict__ Sx) {
    __shared__ unsigned short Ab[128 * 256];   // 64 KB, block-lifetime constant

    const int tid  = threadIdx.x;
    const int lane = tid & 63;
    const int wn   = tid >> 6;        // 0..7: wave's 64-col group
    const int l31  = lane & 31;
    const int hi   = lane >> 5;       // 0/1
    const int cb0  = blockIdx.x * 128;
    float* Ss = Sx + (blockIdx.x & (NSLICE - 1)) * (BATCH * 2);

    // ---- stage A panel-major: (row r, chunk c) -> byte c*2048 + ((r*16)^((c&7)<<4))
    //      Thread handles one 16B chunk: 2 float4 global reads, 1 ds_write_b128.
#pragma unroll
    for (int it = 0; it < 8; ++it) {
        const int idx = it * 512 + tid;      // 4096 tasks = 128 rows x 32 chunks
        const int r = idx >> 5;              // 0..127
        const int c = idx & 31;              // chunk (8 bf16 = 16B)
        int gr = cb0 + r;
        if (gr > TOTC - 1) gr = TOTC - 1;    // clamp; masked in epilogue
        const float4 f0 = *(const float4*)&feats[(size_t)gr * DIM + c * 8];
        const float4 f1 = *(const float4*)&feats[(size_t)gr * DIM + c * 8 + 4];
        uint4 pk;
        pk.x = f2bf(f0.x) | (f2bf(f0.y) << 16);
        pk.y = f2bf(f0.z) | (f2bf(f0.w) << 16);
        pk.z = f2bf(f1.x) | (f2bf(f1.y) << 16);
        pk.w = f2bf(f1.z) | (f2bf(f1.w) << 16);
        *(uint4*)((char*)Ab + c * 2048 + ((r * 16) ^ ((c & 7) << 4))) = pk;
    }
    __syncthreads();                         // the ONLY barrier in this kernel

    const bool mixed = (cb0 < NCL && cb0 + 127 >= NCL) || (cb0 + 127 >= TOTC);
    const int  halfsel = (cb0 >= NCL) ? 1 : 0;

    float sr0[2][2], sr1[2][2];

#pragma unroll
    for (int p = 0; p < 2; ++p) {
        // B bases for this wave's two 32-col fragments (panel hi)
        const unsigned short* bb0 = xnT + (size_t)hi * 8192
                                  + (size_t)(p * 512 + wn * 64 + l31) * 8;
        const unsigned short* bb1 = bb0 + 256;   // +32 cols

        f32x16 acc[4][2];
#pragma unroll
        for (int mt = 0; mt < 4; ++mt) {
            acc[mt][0] = (f32x16)(0.0f);
            acc[mt][1] = (f32x16)(0.0f);
        }

#pragma unroll 4
        for (int kk = 0; kk < 16; ++kk) {
            const bf16x8 b0 = *(const bf16x8*)(bb0 + (size_t)kk * 16384);
            const bf16x8 b1 = *(const bf16x8*)(bb1 + (size_t)kk * 16384);
            const int ch = kk * 2 + hi;
            const int kbase = ch * 2048;
            const int key = (ch & 7) << 4;
#pragma unroll
            for (int mt = 0; mt < 4; ++mt) {
                const bf16x8 a = *(const bf16x8*)((const char*)Ab + kbase
                                   + ((mt * 512 + l31 * 16) ^ key));
                acc[mt][0] = __builtin_amdgcn_mfma_f32_32x32x16_bf16(a, b0, acc[mt][0], 0, 0, 0);
                acc[mt][1] = __builtin_amdgcn_mfma_f32_32x32x16_bf16(a, b1, acc[mt][1], 0, 0, 0);
            }
        }

        // ---- epilogue: e = exp(20*d - 20); sum over all 128 cluster rows ----
        if (!mixed) {
#pragma unroll
            for (int nn = 0; nn < 2; ++nn) {
                float s = 0.0f;
#pragma unroll
                for (int mt = 0; mt < 4; ++mt)
#pragma unroll
                    for (int r = 0; r < 16; ++r)
                        s += __expf(fmaf(acc[mt][nn][r], 20.0f, -20.0f));
                s += __shfl_xor(s, 32, 64);    // combine hi halves (rows +4)
                sr0[p][nn] = s;
                sr1[p][nn] = 0.0f;
            }
        } else {
#pragma unroll
            for (int nn = 0; nn < 2; ++nn) {
                float sh0 = 0.0f, sh1 = 0.0f;
#pragma unroll
                for (int mt = 0; mt < 4; ++mt)
#pragma unroll
                    for (int r = 0; r < 16; ++r) {
                        const int cl = cb0 + mt * 32 +
                                       (r & 3) + 8 * (r >> 2) + 4 * hi;
                        const bool valid = cl < TOTC;
                        float e = __expf(fmaf(acc[mt][nn][r], 20.0f, -20.0f));
                        e = valid ? e : 0.0f;
                        sh0 += (cl < NCL) ? e : 0.0f;
                        sh1 += (cl < NCL) ? 0.0f : e;
                    }
                sh0 += __shfl_xor(sh0, 32, 64);
                sh1 += __shfl_xor(sh1, 32, 64);
                sr0[p][nn] = sh0;
                sr1[p][nn] = sh1;
            }
        }
    }

    // ---- all atomics at the very end: fire-and-forget ----
    if (hi == 0) {
#pragma unroll
        for (int p = 0; p < 2; ++p)
#pragma unroll
            for (int nn = 0; nn < 2; ++nn) {
                const int col = p * 512 + wn * 64 + nn * 32 + l31;
                if (!mixed) {
                    atomicAdd(&Ss[col * 2 + halfsel], sr0[p][nn]);
                } else {
                    atomicAdd(&Ss[col * 2 + 0], sr0[p][nn]);
                    atomicAdd(&Ss[col * 2 + 1], sr1[p][nn]);
                }
            }
    }
}

// ---------------------------------------------------------------------------
// Kernel 3: loss = 0.5 * mean_b[(20+log S0 - z0) + (20+log S1 - z1)],
// summing the 16 slices first.
// ---------------------------------------------------------------------------
__global__ __launch_bounds__(256) void k_loss(const float* __restrict__ Sx,
                                              const float* __restrict__ z,
                                              float* __restrict__ out) {
    const int t = threadIdx.x;
    float part = 0.0f;
    for (int r = t; r < BATCH; r += 256) {
        float s0 = 0.0f, s1 = 0.0f;
#pragma unroll
        for (int sl = 0; sl < NSLICE; ++sl) {
            s0 += Sx[sl * (BATCH * 2) + r * 2 + 0];
            s1 += Sx[sl * (BATCH * 2) + r * 2 + 1];
        }
        part += 40.0f + logf(s0) + logf(s1) - z[r * 2 + 0] - z[r * 2 + 1];
    }
#pragma unroll
    for (int o = 1; o < 64; o <<= 1) part += __shfl_xor(part, o, 64);
    __shared__ float ws[4];
    if ((t & 63) == 0) ws[t >> 6] = part;
    __syncthreads();
    if (t == 0) {
        const float tot = ws[0] + ws[1] + ws[2] + ws[3];
        out[0] = 0.5f * tot / (float)BATCH;
    }
}

// ---------------------------------------------------------------------------
extern "C" void kernel_launch(void* const* d_in, const int* in_sizes, int n_in,
                              void* d_out, int out_size, void* d_ws, size_t ws_size,
                              hipStream_t stream) {
    const float* inputs  = (const float*)d_in[0];
    const int*   targets = (const int*)d_in[1];
    const float* feats   = (const float*)d_in[2];
    float* out = (float*)d_out;

    unsigned short* xnT = (unsigned short*)d_ws;          // 32 panels * 16 KB = 512 KB
    float* Sx = (float*)(xnT + BATCH * DIM);              // 16*1024*2 f32 = 128 KB
    float* zt = Sx + NSLICE * BATCH * 2;                  // 1024*2 f32

    k_prep<<<BATCH, 64, 0, stream>>>(inputs, targets, feats, xnT, Sx, zt);
    const int nblk = (TOTC + 127) / 128;                  // 782
    k_main<<<nblk, 512, 0, stream>>>(xnT, feats, Sx);
    k_loss<<<1, 256, 0, stream>>>(Sx, zt, out);
}

// Round 10
// 94.386 us; speedup vs baseline: 1.0461x; 1.0461x over previous
//
#include <hip/hip_runtime.h>
#include <math.h>

#define BATCH 1024
#define DIM   256
#define NCL   50000
#define TOTC  100000   // 2*NC
#define NSLICE 16

typedef __attribute__((ext_vector_type(8)))  short bf16x8;   // 8 bf16 = 4 VGPR
typedef __attribute__((ext_vector_type(16))) float f32x16;   // 32x32 acc frag

__device__ __forceinline__ unsigned int f2bf(float f) {   // RNE f32 -> bf16
    unsigned int u = __float_as_uint(f);
    return (u + 0x7FFFu + ((u >> 16) & 1u)) >> 16;
}

// ---------------------------------------------------------------------------
// Kernel 1: normalize rows -> bf16 xn stored TRANSPOSED in k-panels:
// element (k, b) lives at panel p=k>>3, byte p*16384 + b*16 + (k&7)*2.
// A 32x32x16-MFMA B-fragment (col=lane&31, k=kk*16+hi*8..+7) is then ONE
// coalesced 16B load (512B runs across lanes). Also: target logits, zero
// sliced accumulators. One wave per batch row.
// ---------------------------------------------------------------------------
__global__ __launch_bounds__(64) void k_prep(const float* __restrict__ in,
                                             const int* __restrict__ tgt,
                                             const float* __restrict__ feats,
                                             unsigned short* __restrict__ xnT,
                                             float* __restrict__ Sx,
                                             float* __restrict__ z) {
    const int b = blockIdx.x;
    const int t = threadIdx.x;           // 0..63, 4 floats each (k = t*4..t*4+3)
    float4 v = *(const float4*)&in[b * DIM + t * 4];
    float ss = v.x * v.x + v.y * v.y + v.z * v.z + v.w * v.w;
#pragma unroll
    for (int o = 1; o < 64; o <<= 1) ss += __shfl_xor(ss, o, 64);
    const float sc = 1.0f / sqrtf(ss);
    float4 w;
    w.x = v.x * sc; w.y = v.y * sc; w.z = v.z * sc; w.w = v.w * sc;

    // panel write: panel = t>>1, within-row byte offset (t&1)*8
    uint2 p;
    p.x = f2bf(w.x) | (f2bf(w.y) << 16);
    p.y = f2bf(w.z) | (f2bf(w.w) << 16);
    *(uint2*)((char*)xnT + (t >> 1) * 16384 + b * 16 + (t & 1) * 8) = p;

    const int tb = tgt[b];
#pragma unroll
    for (int h = 0; h < 2; ++h) {
        const int row = tb + h * NCL;    // mean half rows [0,NC), hard [NC,2NC)
        float4 f = *(const float4*)&feats[row * DIM + t * 4];
        float d = w.x * f.x + w.y * f.y + w.z * f.z + w.w * f.w;
#pragma unroll
        for (int o = 1; o < 64; o <<= 1) d += __shfl_xor(d, o, 64);
        if (t == 0) z[b * 2 + h] = d * 20.0f;
    }
    // zero sliced accumulators: 16*1024*2 = 32768 floats over 1024 blocks
    if (t < 32) Sx[b * 32 + t] = 0.0f;
}

// ---------------------------------------------------------------------------
// Kernel 2: MFMA GEMM + fused sumexp.
// 782 blocks x 4 WAVES (256 thr); block owns 128 clusters. At ~228 unified
// regs (128 AGPR acc + ~100 VGPR) the CU fits 8 waves = TWO independent
// blocks: one block's stage/HBM + B-L2 latency hides under the other's
// MFMA loop (R9's single 8-wave block had nothing co-resident).
// A staged ONCE into 64 KB LDS panel-major (conflict-free b128 reads,
// verified 0 conflicts in R9); ONE barrier; barrier-free main loop.
// Wave = all 128 cluster rows (Mf=4) x 64 batch cols (Nf=2), 4 passes.
// Per kk: 4 ds_read_b128 + 2 coalesced 16B B-loads (xnT, L2) + 8 MFMA.
// Sums -> statically-indexed sregs; atomics once at kernel end.
// ---------------------------------------------------------------------------
__global__ __launch_bounds__(256, 2) void k_main(const unsigned short* __restrict__ xnT,
                                                 const float* __restrict__ feats,
                                                 float* __restrict__ Sx) {
    __shared__ unsigned short Ab[128 * 256];   // 64 KB, block-lifetime constant

    const int tid  = threadIdx.x;
    const int lane = tid & 63;
    const int wn   = tid >> 6;        // 0..3: wave's 64-col group
    const int l31  = lane & 31;
    const int hi   = lane >> 5;       // 0/1
    const int cb0  = blockIdx.x * 128;
    float* Ss = Sx + (blockIdx.x & (NSLICE - 1)) * (BATCH * 2);

    // ---- stage A panel-major: (row r, chunk c) -> byte c*2048 + ((r*16)^((c&7)<<4))
    //      Thread handles one 16B chunk: 2 float4 global reads, 1 ds_write_b128.
#pragma unroll
    for (int it = 0; it < 16; ++it) {
        const int idx = it * 256 + tid;      // 4096 tasks = 128 rows x 32 chunks
        const int r = idx >> 5;              // 0..127
        const int c = idx & 31;              // chunk (8 bf16 = 16B)
        int gr = cb0 + r;
        if (gr > TOTC - 1) gr = TOTC - 1;    // clamp; masked in epilogue
        const float4 f0 = *(const float4*)&feats[(size_t)gr * DIM + c * 8];
        const float4 f1 = *(const float4*)&feats[(size_t)gr * DIM + c * 8 + 4];
        uint4 pk;
        pk.x = f2bf(f0.x) | (f2bf(f0.y) << 16);
        pk.y = f2bf(f0.z) | (f2bf(f0.w) << 16);
        pk.z = f2bf(f1.x) | (f2bf(f1.y) << 16);
        pk.w = f2bf(f1.z) | (f2bf(f1.w) << 16);
        *(uint4*)((char*)Ab + c * 2048 + ((r * 16) ^ ((c & 7) << 4))) = pk;
    }
    __syncthreads();                         // the ONLY barrier in this kernel

    const bool mixed = (cb0 < NCL && cb0 + 127 >= NCL) || (cb0 + 127 >= TOTC);
    const int  halfsel = (cb0 >= NCL) ? 1 : 0;

    float sr0[4][2], sr1[4][2];

#pragma unroll
    for (int p = 0; p < 4; ++p) {
        // B bases for this wave's two 32-col fragments (panel hi)
        const unsigned short* bb0 = xnT + (size_t)hi * 8192
                                  + (size_t)(p * 256 + wn * 64 + l31) * 8;
        const unsigned short* bb1 = bb0 + 256;   // +32 cols

        f32x16 acc[4][2];
#pragma unroll
        for (int mt = 0; mt < 4; ++mt) {
            acc[mt][0] = (f32x16)(0.0f);
            acc[mt][1] = (f32x16)(0.0f);
        }

#pragma unroll 4
        for (int kk = 0; kk < 16; ++kk) {
            const bf16x8 b0 = *(const bf16x8*)(bb0 + (size_t)kk * 16384);
            const bf16x8 b1 = *(const bf16x8*)(bb1 + (size_t)kk * 16384);
            const int ch = kk * 2 + hi;
            const int kbase = ch * 2048;
            const int key = (ch & 7) << 4;
#pragma unroll
            for (int mt = 0; mt < 4; ++mt) {
                const bf16x8 a = *(const bf16x8*)((const char*)Ab + kbase
                                   + ((mt * 512 + l31 * 16) ^ key));
                acc[mt][0] = __builtin_amdgcn_mfma_f32_32x32x16_bf16(a, b0, acc[mt][0], 0, 0, 0);
                acc[mt][1] = __builtin_amdgcn_mfma_f32_32x32x16_bf16(a, b1, acc[mt][1], 0, 0, 0);
            }
        }

        // ---- epilogue: e = exp(20*d - 20); sum over all 128 cluster rows ----
        if (!mixed) {
#pragma unroll
            for (int nn = 0; nn < 2; ++nn) {
                float s = 0.0f;
#pragma unroll
                for (int mt = 0; mt < 4; ++mt)
#pragma unroll
                    for (int r = 0; r < 16; ++r)
                        s += __expf(fmaf(acc[mt][nn][r], 20.0f, -20.0f));
                s += __shfl_xor(s, 32, 64);    // combine hi halves (rows +4)
                sr0[p][nn] = s;
                sr1[p][nn] = 0.0f;
            }
        } else {
#pragma unroll
            for (int nn = 0; nn < 2; ++nn) {
                float sh0 = 0.0f, sh1 = 0.0f;
#pragma unroll
                for (int mt = 0; mt < 4; ++mt)
#pragma unroll
                    for (int r = 0; r < 16; ++r) {
                        const int cl = cb0 + mt * 32 +
                                       (r & 3) + 8 * (r >> 2) + 4 * hi;
                        const bool valid = cl < TOTC;
                        float e = __expf(fmaf(acc[mt][nn][r], 20.0f, -20.0f));
                        e = valid ? e : 0.0f;
                        sh0 += (cl < NCL) ? e : 0.0f;
                        sh1 += (cl < NCL) ? 0.0f : e;
                    }
                sh0 += __shfl_xor(sh0, 32, 64);
                sh1 += __shfl_xor(sh1, 32, 64);
                sr0[p][nn] = sh0;
                sr1[p][nn] = sh1;
            }
        }
    }

    // ---- all atomics at the very end: fire-and-forget ----
    if (hi == 0) {
#pragma unroll
        for (int p = 0; p < 4; ++p)
#pragma unroll
            for (int nn = 0; nn < 2; ++nn) {
                const int col = p * 256 + wn * 64 + nn * 32 + l31;
                if (!mixed) {
                    atomicAdd(&Ss[col * 2 + halfsel], sr0[p][nn]);
                } else {
                    atomicAdd(&Ss[col * 2 + 0], sr0[p][nn]);
                    atomicAdd(&Ss[col * 2 + 1], sr1[p][nn]);
                }
            }
    }
}

// ---------------------------------------------------------------------------
// Kernel 3: loss = 0.5 * mean_b[(20+log S0 - z0) + (20+log S1 - z1)],
// summing the 16 slices first.
// ---------------------------------------------------------------------------
__global__ __launch_bounds__(256) void k_loss(const float* __restrict__ Sx,
                                              const float* __restrict__ z,
                                              float* __restrict__ out) {
    const int t = threadIdx.x;
    float part = 0.0f;
    for (int r = t; r < BATCH; r += 256) {
        float s0 = 0.0f, s1 = 0.0f;
#pragma unroll
        for (int sl = 0; sl < NSLICE; ++sl) {
            s0 += Sx[sl * (BATCH * 2) + r * 2 + 0];
            s1 += Sx[sl * (BATCH * 2) + r * 2 + 1];
        }
        part += 40.0f + logf(s0) + logf(s1) - z[r * 2 + 0] - z[r * 2 + 1];
    }
#pragma unroll
    for (int o = 1; o < 64; o <<= 1) part += __shfl_xor(part, o, 64);
    __shared__ float ws[4];
    if ((t & 63) == 0) ws[t >> 6] = part;
    __syncthreads();
    if (t == 0) {
        const float tot = ws[0] + ws[1] + ws[2] + ws[3];
        out[0] = 0.5f * tot / (float)BATCH;
    }
}

// ---------------------------------------------------------------------------
extern "C" void kernel_launch(void* const* d_in, const int* in_sizes, int n_in,
                              void* d_out, int out_size, void* d_ws, size_t ws_size,
                              hipStream_t stream) {
    const float* inputs  = (const float*)d_in[0];
    const int*   targets = (const int*)d_in[1];
    const float* feats   = (const float*)d_in[2];
    float* out = (float*)d_out;

    unsigned short* xnT = (unsigned short*)d_ws;          // 32 panels * 16 KB = 512 KB
    float* Sx = (float*)(xnT + BATCH * DIM);              // 16*1024*2 f32 = 128 KB
    float* zt = Sx + NSLICE * BATCH * 2;                  // 1024*2 f32

    k_prep<<<BATCH, 64, 0, stream>>>(inputs, targets, feats, xnT, Sx, zt);
    const int nblk = (TOTC + 127) / 128;                  // 782
    k_main<<<nblk, 256, 0, stream>>>(xnT, feats, Sx);
    k_loss<<<1, 256, 0, stream>>>(Sx, zt, out);
}

// Round 11
// 93.376 us; speedup vs baseline: 1.0575x; 1.0108x over previous
//
#include <hip/hip_runtime.h>
#include <math.h>

#define BATCH 1024
#define DIM   256
#define NCL   50000
#define TOTC  100000   // 2*NC
#define NSLICE 16

typedef __attribute__((ext_vector_type(8)))  short bf16x8;   // 8 bf16 = 4 VGPR
typedef __attribute__((ext_vector_type(16))) float f32x16;   // 32x32 acc frag

__device__ __forceinline__ unsigned int f2bf(float f) {   // RNE f32 -> bf16
    unsigned int u = __float_as_uint(f);
    return (u + 0x7FFFu + ((u >> 16) & 1u)) >> 16;
}

// ---------------------------------------------------------------------------
// Kernel 1: normalize rows -> bf16 xn stored TRANSPOSED in k-panels:
// element (k, b) lives at panel p=k>>3, byte p*16384 + b*16 + (k&7)*2.
// A 32x32x16-MFMA B-fragment (col=lane&31, k=kk*16+hi*8..+7) is then ONE
// coalesced 16B load (512B runs across lanes). Also: target logits, zero
// sliced accumulators. One wave per batch row.
// ---------------------------------------------------------------------------
__global__ __launch_bounds__(64) void k_prep(const float* __restrict__ in,
                                             const int* __restrict__ tgt,
                                             const float* __restrict__ feats,
                                             unsigned short* __restrict__ xnT,
                                             float* __restrict__ Sx,
                                             float* __restrict__ z) {
    const int b = blockIdx.x;
    const int t = threadIdx.x;           // 0..63, 4 floats each (k = t*4..t*4+3)
    float4 v = *(const float4*)&in[b * DIM + t * 4];
    float ss = v.x * v.x + v.y * v.y + v.z * v.z + v.w * v.w;
#pragma unroll
    for (int o = 1; o < 64; o <<= 1) ss += __shfl_xor(ss, o, 64);
    const float sc = 1.0f / sqrtf(ss);
    float4 w;
    w.x = v.x * sc; w.y = v.y * sc; w.z = v.z * sc; w.w = v.w * sc;

    // panel write: panel = t>>1, within-row byte offset (t&1)*8
    uint2 p;
    p.x = f2bf(w.x) | (f2bf(w.y) << 16);
    p.y = f2bf(w.z) | (f2bf(w.w) << 16);
    *(uint2*)((char*)xnT + (t >> 1) * 16384 + b * 16 + (t & 1) * 8) = p;

    const int tb = tgt[b];
#pragma unroll
    for (int h = 0; h < 2; ++h) {
        const int row = tb + h * NCL;    // mean half rows [0,NC), hard [NC,2NC)
        float4 f = *(const float4*)&feats[row * DIM + t * 4];
        float d = w.x * f.x + w.y * f.y + w.z * f.z + w.w * f.w;
#pragma unroll
        for (int o = 1; o < 64; o <<= 1) d += __shfl_xor(d, o, 64);
        if (t == 0) z[b * 2 + h] = d * 20.0f;
    }
    // zero sliced accumulators: 16*1024*2 = 32768 floats over 1024 blocks
    if (t < 32) Sx[b * 32 + t] = 0.0f;
}

// ---------------------------------------------------------------------------
// Kernel 2: MFMA GEMM + fused sumexp.
// 1563 blocks x 4 waves (256 thr); block owns 64 clusters (32 KB LDS).
// acc[2][2] = 64 AGPR (vs R10's 128): with __launch_bounds__(256,3) the
// unified reg budget is 168 -> 3 waves/SIMD -> THREE co-resident blocks
// (96 KB LDS), breaking the 8-wave/CU plateau of R8-R10.
// A (feature rows, f32->bf16) staged ONCE panel-major (conflict-free b128
// reads, 0 conflicts measured in R9/R10); ONE barrier; barrier-free main
// loop. Wave = 64 cluster rows (Mf=2) x 64 batch cols (Nf=2), 4 passes
// over batch. Per kk: 2 ds_read_b128 + 2 coalesced 16B B-loads (xnT, L2)
// + 4 MFMA. Sums -> statically-indexed sregs; atomics once at kernel end.
// ---------------------------------------------------------------------------
__global__ __launch_bounds__(256, 3) void k_main(const unsigned short* __restrict__ xnT,
                                                 const float* __restrict__ feats,
                                                 float* __restrict__ Sx) {
    __shared__ unsigned short Ab[64 * 256];   // 32 KB, block-lifetime constant

    const int tid  = threadIdx.x;
    const int lane = tid & 63;
    const int wn   = tid >> 6;        // 0..3: wave's 64-col group
    const int l31  = lane & 31;
    const int hi   = lane >> 5;       // 0/1
    const int cb0  = blockIdx.x * 64;
    float* Ss = Sx + (blockIdx.x & (NSLICE - 1)) * (BATCH * 2);

    // ---- stage A panel-major: (row r, chunk c) -> byte c*1024 + ((r*16)^((c&7)<<4))
    //      Thread handles one 16B chunk: 2 float4 global reads, 1 ds_write_b128.
#pragma unroll
    for (int it = 0; it < 8; ++it) {
        const int idx = it * 256 + tid;      // 2048 tasks = 64 rows x 32 chunks
        const int r = idx >> 5;              // 0..63
        const int c = idx & 31;              // chunk (8 bf16 = 16B)
        int gr = cb0 + r;
        if (gr > TOTC - 1) gr = TOTC - 1;    // clamp; masked in epilogue
        const float4 f0 = *(const float4*)&feats[(size_t)gr * DIM + c * 8];
        const float4 f1 = *(const float4*)&feats[(size_t)gr * DIM + c * 8 + 4];
        uint4 pk;
        pk.x = f2bf(f0.x) | (f2bf(f0.y) << 16);
        pk.y = f2bf(f0.z) | (f2bf(f0.w) << 16);
        pk.z = f2bf(f1.x) | (f2bf(f1.y) << 16);
        pk.w = f2bf(f1.z) | (f2bf(f1.w) << 16);
        *(uint4*)((char*)Ab + c * 1024 + ((r * 16) ^ ((c & 7) << 4))) = pk;
    }
    __syncthreads();                         // the ONLY barrier in this kernel

    const bool mixed = (cb0 < NCL && cb0 + 63 >= NCL) || (cb0 + 63 >= TOTC);
    const int  halfsel = (cb0 >= NCL) ? 1 : 0;

    float sr0[4][2], sr1[4][2];

#pragma unroll
    for (int p = 0; p < 4; ++p) {
        // B bases for this wave's two 32-col fragments (panel hi)
        const unsigned short* bb0 = xnT + (size_t)hi * 8192
                                  + (size_t)(p * 256 + wn * 64 + l31) * 8;
        const unsigned short* bb1 = bb0 + 256;   // +32 cols

        f32x16 acc[2][2];
#pragma unroll
        for (int mt = 0; mt < 2; ++mt) {
            acc[mt][0] = (f32x16)(0.0f);
            acc[mt][1] = (f32x16)(0.0f);
        }

#pragma unroll 4
        for (int kk = 0; kk < 16; ++kk) {
            const bf16x8 b0 = *(const bf16x8*)(bb0 + (size_t)kk * 16384);
            const bf16x8 b1 = *(const bf16x8*)(bb1 + (size_t)kk * 16384);
            const int ch = kk * 2 + hi;
            const int kbase = ch * 1024;
            const int key = (ch & 7) << 4;
#pragma unroll
            for (int mt = 0; mt < 2; ++mt) {
                const bf16x8 a = *(const bf16x8*)((const char*)Ab + kbase
                                   + ((mt * 512 + l31 * 16) ^ key));
                acc[mt][0] = __builtin_amdgcn_mfma_f32_32x32x16_bf16(a, b0, acc[mt][0], 0, 0, 0);
                acc[mt][1] = __builtin_amdgcn_mfma_f32_32x32x16_bf16(a, b1, acc[mt][1], 0, 0, 0);
            }
        }

        // ---- epilogue: e = exp(20*d - 20); sum over all 64 cluster rows ----
        if (!mixed) {
#pragma unroll
            for (int nn = 0; nn < 2; ++nn) {
                float s = 0.0f;
#pragma unroll
                for (int mt = 0; mt < 2; ++mt)
#pragma unroll
                    for (int r = 0; r < 16; ++r)
                        s += __expf(fmaf(acc[mt][nn][r], 20.0f, -20.0f));
                s += __shfl_xor(s, 32, 64);    // combine hi halves (rows +4)
                sr0[p][nn] = s;
                sr1[p][nn] = 0.0f;
            }
        } else {
#pragma unroll
            for (int nn = 0; nn < 2; ++nn) {
                float sh0 = 0.0f, sh1 = 0.0f;
#pragma unroll
                for (int mt = 0; mt < 2; ++mt)
#pragma unroll
                    for (int r = 0; r < 16; ++r) {
                        const int cl = cb0 + mt * 32 +
                                       (r & 3) + 8 * (r >> 2) + 4 * hi;
                        const bool valid = cl < TOTC;
                        float e = __expf(fmaf(acc[mt][nn][r], 20.0f, -20.0f));
                        e = valid ? e : 0.0f;
                        sh0 += (cl < NCL) ? e : 0.0f;
                        sh1 += (cl < NCL) ? 0.0f : e;
                    }
                sh0 += __shfl_xor(sh0, 32, 64);
                sh1 += __shfl_xor(sh1, 32, 64);
                sr0[p][nn] = sh0;
                sr1[p][nn] = sh1;
            }
        }
    }

    // ---- all atomics at the very end: fire-and-forget ----
    if (hi == 0) {
#pragma unroll
        for (int p = 0; p < 4; ++p)
#pragma unroll
            for (int nn = 0; nn < 2; ++nn) {
                const int col = p * 256 + wn * 64 + nn * 32 + l31;
                if (!mixed) {
                    atomicAdd(&Ss[col * 2 + halfsel], sr0[p][nn]);
                } else {
                    atomicAdd(&Ss[col * 2 + 0], sr0[p][nn]);
                    atomicAdd(&Ss[col * 2 + 1], sr1[p][nn]);
                }
            }
    }
}

// ---------------------------------------------------------------------------
// Kernel 3: loss = 0.5 * mean_b[(20+log S0 - z0) + (20+log S1 - z1)],
// summing the 16 slices first.
// ---------------------------------------------------------------------------
__global__ __launch_bounds__(256) void k_loss(const float* __restrict__ Sx,
                                              const float* __restrict__ z,
                                              float* __restrict__ out) {
    const int t = threadIdx.x;
    float part = 0.0f;
    for (int r = t; r < BATCH; r += 256) {
        float s0 = 0.0f, s1 = 0.0f;
#pragma unroll
        for (int sl = 0; sl < NSLICE; ++sl) {
            s0 += Sx[sl * (BATCH * 2) + r * 2 + 0];
            s1 += Sx[sl * (BATCH * 2) + r * 2 + 1];
        }
        part += 40.0f + logf(s0) + logf(s1) - z[r * 2 + 0] - z[r * 2 + 1];
    }
#pragma unroll
    for (int o = 1; o < 64; o <<= 1) part += __shfl_xor(part, o, 64);
    __shared__ float ws[4];
    if ((t & 63) == 0) ws[t >> 6] = part;
    __syncthreads();
    if (t == 0) {
        const float tot = ws[0] + ws[1] + ws[2] + ws[3];
        out[0] = 0.5f * tot / (float)BATCH;
    }
}

// ---------------------------------------------------------------------------
extern "C" void kernel_launch(void* const* d_in, const int* in_sizes, int n_in,
                              void* d_out, int out_size, void* d_ws, size_t ws_size,
                              hipStream_t stream) {
    const float* inputs  = (const float*)d_in[0];
    const int*   targets = (const int*)d_in[1];
    const float* feats   = (const float*)d_in[2];
    float* out = (float*)d_out;

    unsigned short* xnT = (unsigned short*)d_ws;          // 32 panels * 16 KB = 512 KB
    float* Sx = (float*)(xnT + BATCH * DIM);              // 16*1024*2 f32 = 128 KB
    float* zt = Sx + NSLICE * BATCH * 2;                  // 1024*2 f32

    k_prep<<<BATCH, 64, 0, stream>>>(inputs, targets, feats, xnT, Sx, zt);
    const int nblk = (TOTC + 63) / 64;                    // 1563
    k_main<<<nblk, 256, 0, stream>>>(xnT, feats, Sx);
    k_loss<<<1, 256, 0, stream>>>(Sx, zt, out);
}